// Round 1
// baseline (1087.666 us; speedup 1.0000x reference)
//
#include <hip/hip_runtime.h>
#include <math.h>

#define NB 32
#define CC 256
#define LL 6
#define TT 64
#define VV 50
#define CI 64
#define KK 3
#define EPSF 1e-5f

// LAYERS flattened (with duplicates, exactly as reference)
__device__ __constant__ int c_lay[94] = {
  1,0,20,26,25,45,
  0,20,12,16,2,4,8,25,45,37,41,27,29,33,
  12,16,2,4,8,13,17,3,5,9,3,28,37,41,27,29,33,38,42,28,30,34,
  13,17,3,5,9,14,18,6,10,3,28,38,42,28,30,34,39,43,31,35,
  14,18,6,10,15,19,7,11,39,43,31,35,40,44,32,36,
  15,19,7,11,21,22,23,24,40,44,32,36,46,47,48,49
};
__device__ __constant__ int c_off[6] = {0,6,20,42,62,78};
__device__ __constant__ int c_cnt[6] = {6,14,22,20,16,16};

// ---- K1: x_t = max over T.  out: (N,C,L,V) ----
__global__ void k_max_t(const float* __restrict__ x, float* __restrict__ xt) {
    int idx = blockIdx.x * 256 + threadIdx.x;          // N*C*L*V = 2,457,600
    const float* p = x + (size_t)(idx / VV) * (TT * VV) + (idx % VV);
    float m = -INFINITY;
#pragma unroll 8
    for (int t = 0; t < TT; ++t) m = fmaxf(m, p[t * VV]);
    xt[idx] = m;
}

// ---- K2: y = W_down @ x_t + b_down.  out: (N,CI,L,V) ----
__global__ void k_down(const float* __restrict__ xt, const float* __restrict__ Wd,
                       const float* __restrict__ bd, float* __restrict__ y) {
    int idx = blockIdx.x * 256 + threadIdx.x;          // N*(CI/4)*L*V = 153,600
    int v = idx % VV; int r = idx / VV;
    int l = r % LL;  r /= LL;
    int dq = r % (CI / 4); int n = r / (CI / 4);
    int d0 = dq * 4;
    const float* xp = xt + ((size_t)(n * CC) * LL + l) * VV + v;  // c-stride = L*V
    float a0 = 0.f, a1 = 0.f, a2 = 0.f, a3 = 0.f;
    for (int c = 0; c < CC; ++c) {
        float xv = xp[(size_t)c * (LL * VV)];
        a0 += Wd[(d0 + 0) * CC + c] * xv;
        a1 += Wd[(d0 + 1) * CC + c] * xv;
        a2 += Wd[(d0 + 2) * CC + c] * xv;
        a3 += Wd[(d0 + 3) * CC + c] * xv;
    }
    size_t ob = ((size_t)(n * CI + d0) * LL + l) * VV + v;
    y[ob]                = a0 + bd[d0 + 0];
    y[ob + 1 * LL * VV]  = a1 + bd[d0 + 1];
    y[ob + 2 * LL * VV]  = a2 + bd[d0 + 2];
    y[ob + 3 * LL * VV]  = a3 + bd[d0 + 3];
}

// ---- K3: BN1 stats (per-channel over N,L,V) + relu + layer-mean -> xs (N,CI,L) ----
__global__ void k_bn1_xs(const float* __restrict__ y, const float* __restrict__ g1,
                         const float* __restrict__ b1, float* __restrict__ xs) {
    int d = blockIdx.x;            // 64 blocks
    int tid = threadIdx.x;         // 256 threads
    const int NE = NB * LL * VV;   // 9600
    double s = 0.0, s2 = 0.0;
    for (int i = tid; i < NE; i += 256) {
        int n = i / (LL * VV); int lv = i % (LL * VV);
        float val = y[(size_t)(n * CI + d) * (LL * VV) + lv];
        s += val; s2 += (double)val * val;
    }
    __shared__ double sh[256], sh2[256];
    sh[tid] = s; sh2[tid] = s2;
    __syncthreads();
    for (int w = 128; w > 0; w >>= 1) {
        if (tid < w) { sh[tid] += sh[tid + w]; sh2[tid] += sh2[tid + w]; }
        __syncthreads();
    }
    __shared__ float s_mean, s_rstd;
    if (tid == 0) {
        double mean = sh[0] / NE;
        double var = sh2[0] / NE - mean * mean;
        s_mean = (float)mean;
        s_rstd = (float)(1.0 / sqrt(var + (double)EPSF));
    }
    __syncthreads();
    float mean = s_mean, rstd = s_rstd, gg = g1[d], bb = b1[d];
    if (tid < NB * LL) {
        int n = tid / LL, l = tid % LL;
        int cnt = c_cnt[l], off = c_off[l];
        const float* yp = y + (size_t)(n * CI + d) * (LL * VV) + l * VV;
        float acc = 0.f;
        for (int j = 0; j < cnt; ++j) {
            float val = yp[c_lay[off + j]];
            float nr = (val - mean) * rstd * gg + bb;
            acc += fmaxf(nr, 0.f);
        }
        xs[(size_t)(n * CI + d) * LL + l] = acc / (float)cnt;
    }
}

// ---- K4: per-n pd/top-k + edge GEMM -> e_pre (N,CI,L,K), idx (N,L,K) ----
__global__ void k_edge(const float* __restrict__ xs, const float* __restrict__ We,
                       float* __restrict__ e_pre, int* __restrict__ idxo) {
    int n = blockIdx.x;           // 32 blocks
    int tid = threadIdx.x;        // 64 threads
    __shared__ float xsh[CI][LL];     // xs[n][c][l]
    __shared__ float xx[LL];
    __shared__ float pd[LL][LL];
    __shared__ int idxs[LL][KK];
    for (int l = 0; l < LL; ++l) xsh[tid][l] = xs[(size_t)(n * CI + tid) * LL + l];
    __syncthreads();
    if (tid < LL) {
        float a = 0.f;
        for (int c = 0; c < CI; ++c) a += xsh[c][tid] * xsh[c][tid];
        xx[tid] = a;
    }
    __syncthreads();
    if (tid < LL * LL) {
        int l = tid / LL, m = tid % LL;
        float inner = 0.f;
        for (int c = 0; c < CI; ++c) inner += xsh[c][l] * xsh[c][m];
        pd[l][m] = 2.f * inner - xx[l] - xx[m];
    }
    __syncthreads();
    if (tid < LL) {
        bool used[LL] = {false, false, false, false, false, false};
        for (int k = 0; k < KK; ++k) {
            float best = -INFINITY; int bi = 0;
            for (int m = 0; m < LL; ++m)
                if (!used[m] && pd[tid][m] > best) { best = pd[tid][m]; bi = m; }
            used[bi] = true;
            idxs[tid][k] = bi;
            idxo[(n * LL + tid) * KK + k] = bi;
        }
    }
    __syncthreads();
    // e_pre[d][l][k] = sum_c We[d][c]*(feat-center) + sum_c We[d][64+c]*center
    int d = tid;
    for (int l = 0; l < LL; ++l) {
        for (int k = 0; k < KK; ++k) {
            int j = idxs[l][k];
            float acc = 0.f;
            for (int c = 0; c < CI; ++c)
                acc += We[d * (2 * CI) + c] * (xsh[c][j] - xsh[c][l]);
            for (int c = 0; c < CI; ++c)
                acc += We[d * (2 * CI) + CI + c] * xsh[c][l];
            e_pre[((size_t)(n * CI + d) * LL + l) * KK + k] = acc;
        }
    }
}

// ---- K5: BN2 stats (per-channel over N,L,K) + leaky-relu + max over k -> e_max (N,CI,L) ----
__global__ void k_bn2_max(const float* __restrict__ e_pre, const float* __restrict__ g2,
                          const float* __restrict__ b2, float* __restrict__ emax) {
    int d = blockIdx.x;            // 64 blocks
    int tid = threadIdx.x;         // 256 threads
    const int NE = NB * LL * KK;   // 576
    double s = 0.0, s2 = 0.0;
    for (int i = tid; i < NE; i += 256) {
        int n = i / (LL * KK); int lk = i % (LL * KK);
        float val = e_pre[(size_t)(n * CI + d) * (LL * KK) + lk];
        s += val; s2 += (double)val * val;
    }
    __shared__ double sh[256], sh2[256];
    sh[tid] = s; sh2[tid] = s2;
    __syncthreads();
    for (int w = 128; w > 0; w >>= 1) {
        if (tid < w) { sh[tid] += sh[tid + w]; sh2[tid] += sh2[tid + w]; }
        __syncthreads();
    }
    __shared__ float s_mean, s_rstd;
    if (tid == 0) {
        double mean = sh[0] / NE;
        double var = sh2[0] / NE - mean * mean;
        s_mean = (float)mean;
        s_rstd = (float)(1.0 / sqrt(var + (double)EPSF));
    }
    __syncthreads();
    float mean = s_mean, rstd = s_rstd, gg = g2[d], bb = b2[d];
    if (tid < NB * LL) {
        int n = tid / LL, l = tid % LL;
        const float* ep = e_pre + ((size_t)(n * CI + d) * LL + l) * KK;
        float m = -INFINITY;
        for (int k = 0; k < KK; ++k) {
            float nr = (ep[k] - mean) * rstd * gg + bb;
            nr = (nr > 0.f) ? nr : 0.2f * nr;   // leaky relu 0.2
            m = fmaxf(m, nr);
        }
        emax[(size_t)(n * CI + d) * LL + l] = m;
    }
}

// ---- K6: att = sigmoid(W_agg @ e_max + b_agg).  out: (N,C,L) ----
__global__ void k_att(const float* __restrict__ emax, const float* __restrict__ Wa,
                      const float* __restrict__ ba, float* __restrict__ att) {
    int idx = blockIdx.x * 256 + threadIdx.x;    // N*C*L = 49,152
    int l = idx % LL; int c = (idx / LL) % CC; int n = idx / (LL * CC);
    float acc = ba[c];
    const float* ep = emax + (size_t)(n * CI) * LL + l;   // d-stride = L
    for (int d = 0; d < CI; ++d)
        acc += Wa[c * CI + d] * ep[(size_t)d * LL];
    att[idx] = 1.f / (1.f + expf(-acc));
}

// ---- K7: out = sum_l x * att.  out: (N,C,T,V) ----
__global__ void k_out(const float* __restrict__ x, const float* __restrict__ att,
                      float* __restrict__ out) {
    int idx = blockIdx.x * 256 + threadIdx.x;    // N*C*T*V = 26,214,400
    int v = idx % VV; int r = idx / VV;
    int t = r % TT;  r /= TT;
    int c = r % CC;  int n = r / CC;
    const float* xp = x + (((size_t)(n * CC + c) * LL) * TT + t) * VV + v;  // l-stride = T*V
    const float* ap = att + (size_t)(n * CC + c) * LL;
    float acc = 0.f;
#pragma unroll
    for (int l = 0; l < LL; ++l) acc += xp[(size_t)l * (TT * VV)] * ap[l];
    out[idx] = acc;
}

extern "C" void kernel_launch(void* const* d_in, const int* in_sizes, int n_in,
                              void* d_out, int out_size, void* d_ws, size_t ws_size,
                              hipStream_t stream) {
    const float* x     = (const float*)d_in[0];
    const float* Wd    = (const float*)d_in[1];
    const float* bd    = (const float*)d_in[2];
    const float* g1    = (const float*)d_in[3];
    const float* b1    = (const float*)d_in[4];
    const float* We    = (const float*)d_in[5];
    const float* g2    = (const float*)d_in[6];
    const float* b2    = (const float*)d_in[7];
    const float* Wa    = (const float*)d_in[8];
    const float* ba    = (const float*)d_in[9];
    float* out = (float*)d_out;

    float* ws = (float*)d_ws;
    float* xt    = ws;                            // 2,457,600
    float* y     = xt + (size_t)NB * CC * LL * VV;     // 614,400
    float* xs    = y + (size_t)NB * CI * LL * VV;      // 12,288
    float* e_pre = xs + (size_t)NB * CI * LL;          // 36,864
    float* emax  = e_pre + (size_t)NB * CI * LL * KK;  // 12,288
    float* att   = emax + (size_t)NB * CI * LL;        // 49,152
    int*   idxb  = (int*)(att + (size_t)NB * CC * LL); // 576 ints

    k_max_t <<<9600,   256, 0, stream>>>(x, xt);
    k_down  <<<600,    256, 0, stream>>>(xt, Wd, bd, y);
    k_bn1_xs<<<64,     256, 0, stream>>>(y, g1, b1, xs);
    k_edge  <<<32,      64, 0, stream>>>(xs, We, e_pre, idxb);
    k_bn2_max<<<64,    256, 0, stream>>>(e_pre, g2, b2, emax);
    k_att   <<<192,    256, 0, stream>>>(emax, Wa, ba, att);
    k_out   <<<102400, 256, 0, stream>>>(x, att, out);
}